// Round 2
// baseline (48.704 us; speedup 1.0000x reference)
//
#include <hip/hip_runtime.h>
#include <cmath>
#include <complex>

// ChebyUpsample: x (256, 32768) f32 -> repeat x2 -> reverse -> cheby1(8,0.05,0.5)
// 4-biquad cascade -> reverse -> y (256, 65536) f32.
// Reversed-time chunked IIR: 1024 chunks/row, 32 input samples (64 outputs) per
// thread, warm-up W=128 steps (dominant pole 0.933 -> residual ~9e-5 vs 0.1 thr).
// Threads near the reversed-time start clamp their warm-up to the true signal
// start with zero state -> exact prefix.

struct SosC {
  float g;       // kz gain folded into section-0 input
  float a1[4];
  float a2[4];
};

__global__ __launch_bounds__(256)
void cheby_up_kernel(const float* __restrict__ x, float* __restrict__ y, SosC c) {
  const int T_IN = 32768;
  const int row = blockIdx.y;
  const int k = blockIdx.x * 256 + threadIdx.x;   // chunk id, 0..1023
  const float* xr = x + (size_t)row * T_IN;
  float* yr = y + (size_t)row * (size_t)(2 * T_IN);

  const float g = c.g;
  const float a10 = c.a1[0], a20 = c.a2[0];
  const float a11 = c.a1[1], a21 = c.a2[1];
  const float a12 = c.a1[2], a22 = c.a2[2];
  const float a13 = c.a1[3], a23 = c.a2[3];

  // transposed direct-form II states, 4 sections
  float z10=0.f, z20=0.f, z11=0.f, z21=0.f;
  float z12=0.f, z22=0.f, z13=0.f, z23=0.f;

  // chunk owns input indices [je, je+31] -> forward outputs [2*je, 2*je+63]
  const int je = T_IN - 32 - 32 * k;

  auto step = [&](float x0) -> float {
    float y0 = x0 + z10;
    z10 = fmaf(-a10, y0, fmaf(2.f, x0, z20));
    z20 = fmaf(-a20, y0, x0);
    float y1 = y0 + z11;
    z11 = fmaf(-a11, y1, fmaf(2.f, y0, z21));
    z21 = fmaf(-a21, y1, y0);
    float y2 = y1 + z12;
    z12 = fmaf(-a12, y2, fmaf(2.f, y1, z22));
    z22 = fmaf(-a22, y2, y1);
    float y3 = y2 + z13;
    z13 = fmaf(-a13, y3, fmaf(2.f, y2, z23));
    z23 = fmaf(-a23, y3, y2);
    return y3;
  };

  // ---- warm-up: inputs [je+32, min(je+96, T_IN)), descending, 2 steps each ----
  {
    const int wlo = je + 32;
    int whi = wlo + 64;
    if (whi > T_IN) whi = T_IN;       // clamp => exact prefix for top chunks
    for (int j = whi - 4; j >= wlo; j -= 4) {
      float4 xx = *reinterpret_cast<const float4*>(xr + j);  // x[j..j+3]
      float s3 = g * xx.w, s2 = g * xx.z, s1 = g * xx.y, s0 = g * xx.x;
      step(s3); step(s3); step(s2); step(s2);
      step(s1); step(s1); step(s0); step(s0);
    }
  }

  // ---- main: 4 groups x 8 inputs = 32 inputs -> 64 outputs ----
  // Reversed-time ascending == forward-time descending: input m yields forward
  // outputs 2m+1 then 2m.
  #pragma unroll
  for (int u = 0; u < 4; ++u) {
    const int j = je + 24 - 8 * u;
    float4 xhi = *reinterpret_cast<const float4*>(xr + j + 4); // x[j+4..j+7]
    float4 xlo = *reinterpret_cast<const float4*>(xr + j);     // x[j..j+3]
    float o[16];
    float s;
    s = g * xhi.w; o[15] = step(s); o[14] = step(s);
    s = g * xhi.z; o[13] = step(s); o[12] = step(s);
    s = g * xhi.y; o[11] = step(s); o[10] = step(s);
    s = g * xhi.x; o[9]  = step(s); o[8]  = step(s);
    s = g * xlo.w; o[7]  = step(s); o[6]  = step(s);
    s = g * xlo.z; o[5]  = step(s); o[4]  = step(s);
    s = g * xlo.y; o[3]  = step(s); o[2]  = step(s);
    s = g * xlo.x; o[1]  = step(s); o[0]  = step(s);
    // 16 consecutive outputs = one full 64B line (2*j is a multiple of 16)
    float* yp = yr + 2 * j;
    *reinterpret_cast<float4*>(yp)      = make_float4(o[0],  o[1],  o[2],  o[3]);
    *reinterpret_cast<float4*>(yp + 4)  = make_float4(o[4],  o[5],  o[6],  o[7]);
    *reinterpret_cast<float4*>(yp + 8)  = make_float4(o[8],  o[9],  o[10], o[11]);
    *reinterpret_cast<float4*>(yp + 12) = make_float4(o[12], o[13], o[14], o[15]);
  }
}

// Host-side replication of _cheby1_sos(8, 0.05, 0.5) in double precision.
static SosC compute_coefs() {
  const int N = 8;
  const double rp = 0.05, Wn = 0.5;
  const double PI = 3.14159265358979323846;
  double eps = std::sqrt(std::pow(10.0, 0.1 * rp) - 1.0);
  double mu = std::asinh(1.0 / eps) / (double)N;
  std::complex<double> p[8];
  std::complex<double> prodNegP(1.0, 0.0);
  int idx = 0;
  for (int m = -N + 1; m < N; m += 2) {
    double theta = PI * (double)m / (2.0 * N);
    std::complex<double> pp = -std::sinh(std::complex<double>(mu, theta));
    p[idx++] = pp;
    prodNegP *= -pp;
  }
  double k = prodNegP.real();
  k /= std::sqrt(1.0 + eps * eps);          // even N
  const double fs = 2.0;
  double warped = 2.0 * fs * std::tan(PI * Wn / fs);
  for (int i = 0; i < 8; i++) p[i] *= warped;
  k *= std::pow(warped, (double)N);
  const double fs2 = 2.0 * fs;
  std::complex<double> prodDen(1.0, 0.0);
  for (int i = 0; i < 8; i++) prodDen *= (fs2 - p[i]);
  double kz = k * (1.0 / prodDen).real();

  SosC c;
  int s = 0;
  for (int i = 0; i < 8; i++) {
    std::complex<double> pz = (fs2 + p[i]) / (fs2 - p[i]);
    if (pz.imag() > 0.0) {                  // same selection order as numpy
      c.a1[s] = (float)(-2.0 * pz.real());
      c.a2[s] = (float)std::norm(pz);       // |pz|^2
      s++;
    }
  }
  c.g = (float)kz;
  return c;
}

extern "C" void kernel_launch(void* const* d_in, const int* in_sizes, int n_in,
                              void* d_out, int out_size, void* d_ws, size_t ws_size,
                              hipStream_t stream) {
  const float* x = (const float*)d_in[0];
  float* y = (float*)d_out;
  SosC c = compute_coefs();
  int rows = in_sizes[0] / 32768;   // 256
  dim3 grid(4, rows);               // 1024 chunks/row, 256 threads/block
  cheby_up_kernel<<<grid, 256, 0, stream>>>(x, y, c);
}